// Round 4
// baseline (83.791 us; speedup 1.0000x reference)
//
#include <hip/hip_runtime.h>
#include <cstddef>

#define BB 4
#define CC 64
#define NN 8192
#define KK 16
#define OO 128

#define SH 136   // LDS row stride (bf16 elems) for h tile: 272B rows, 16B aligned, breaks bank aliasing

typedef __attribute__((ext_vector_type(8))) short bf16x8;
typedef __attribute__((ext_vector_type(4))) float f32x4;

__device__ __forceinline__ unsigned short f2b(float f) {
    unsigned u = __builtin_bit_cast(unsigned, f);
    unsigned r = (u + 0x7fffu + ((u >> 16) & 1u)) >> 16;   // RNE
    return (unsigned short)r;
}

__device__ __forceinline__ float bclo(unsigned d) {       // low bf16 -> f32
    return __builtin_bit_cast(float, d << 16);
}
__device__ __forceinline__ float bchi(unsigned d) {       // high bf16 -> f32
    return __builtin_bit_cast(float, d & 0xffff0000u);
}

// XCD-aware decode: assuming block->XCD = blockIdx%8 on MI355X (8 XCDs),
// batch b = i&3 puts each batch on exactly 2 XCDs -> its 1 MB xt slice stays
// L2-resident. Perf heuristic only; correctness is mapping-independent.
__device__ __forceinline__ void decode_block(int i, int& b, int& n_base) {
    b = i & 3;
    int nblk = ((i >> 2) & 1) * 64 + (i >> 3);   // [0,128)
    n_base = nblk * 64;
}

// x: (B, C, N) fp32 -> xt: (B, N, C) bf16.  Also (16 blocks) W fp32 -> Wbf bf16.
__global__ __launch_bounds__(256) void transpose_kernel(
        const float* __restrict__ x, unsigned short* __restrict__ xt,
        const float* __restrict__ W, unsigned short* __restrict__ Wbf) {
    __shared__ float tile[64][65];
    int b, n0;
    decode_block(blockIdx.x, b, n0);
    const int t  = threadIdx.x;
    const int ln = t & 63;
    const int r  = t >> 6;

    const float* xb = x + (size_t)b * CC * NN;
    #pragma unroll
    for (int s = 0; s < 64; s += 4) {
        int c = s + r;
        tile[c][ln] = xb[(size_t)c * NN + n0 + ln];
    }
    __syncthreads();
    unsigned short* xtb = xt + ((size_t)b * NN + n0) * CC;
    #pragma unroll
    for (int s = 0; s < 64; s += 4) {
        int n = s + r;
        xtb[n * CC + ln] = f2b(tile[ln][n]);
    }

    if (blockIdx.x < 16) {
        int idx = blockIdx.x * 1024 + t * 4;
        float4 v = *reinterpret_cast<const float4*>(W + idx);
        ushort4 o;
        o.x = f2b(v.x); o.y = f2b(v.y); o.z = f2b(v.z); o.w = f2b(v.w);
        *reinterpret_cast<ushort4*>(Wbf + idx) = o;
    }
}

// xt: (B,N,64) bf16; Wbf: (128,128) bf16; eidx: (2,B,N,16); bias: (128); out: (B,128,N) fp32
__global__ __launch_bounds__(256, 4) void main_kernel(
        const unsigned short* __restrict__ xt,
        const unsigned short* __restrict__ Wbf,
        const int*            __restrict__ eidx,
        const float*          __restrict__ bias,
        float*                __restrict__ out) {
    __shared__ unsigned short hl[64 * SH];    // h as bf16, [node][k], k=2c+{0,1}
    __shared__ int eL[2048];                  // [0..1023]=e0 slab, [1024..2047]=e1 slab

    const int t    = threadIdx.x;
    const int lane = t & 63;
    const int w    = t >> 6;
    int b, n_base;
    decode_block(blockIdx.x, b, n_base);

    // ---- stage indices (coalesced int4) ----
    const int* e0 = eidx + ((size_t)b * NN + n_base) * KK;
    const int* e1 = e0 + (size_t)BB * NN * KK;
    *reinterpret_cast<int4*>(&eL[t * 4])        = *reinterpret_cast<const int4*>(e0 + t * 4);
    *reinterpret_cast<int4*>(&eL[1024 + t * 4]) = *reinterpret_cast<const int4*>(e1 + t * 4);
    __syncthreads();   // eL visible

    // ---- phase 1: gather + max; 8 lanes per node row; both node-batches
    //      interleaved so 16 independent 128B gathers are in flight ----
    const unsigned short* xtb = xt + (size_t)b * NN * CC;
    const int g = lane >> 3;     // node within batch of 8
    const int p = lane & 7;      // 16B chunk (channels p*8 .. p*8+7)
    const int nl0 = w * 16 + g;  // batch-0 node
    const int nl1 = nl0 + 8;     // batch-1 node

    uint4 xr0 = *reinterpret_cast<const uint4*>(xtb + (size_t)(n_base + nl0) * CC + p * 8);
    uint4 xr1 = *reinterpret_cast<const uint4*>(xtb + (size_t)(n_base + nl1) * CC + p * 8);

    float m0[8], m1[8];
    #pragma unroll
    for (int j = 0; j < 8; j++) { m0[j] = -1e30f; m1[j] = -1e30f; }

    for (int q = 0; q < 4; q++) {
        // indices: one ds_read_b128 per (bt, list)
        int4 kj0 = *reinterpret_cast<const int4*>(&eL[nl0 * KK + q * 4]);
        int4 ki0 = *reinterpret_cast<const int4*>(&eL[1024 + nl0 * KK + q * 4]);
        int4 kj1 = *reinterpret_cast<const int4*>(&eL[nl1 * KK + q * 4]);
        int4 ki1 = *reinterpret_cast<const int4*>(&eL[1024 + nl1 * KK + q * 4]);
        int ja[8] = {kj0.x, kj0.y, kj0.z, kj0.w, kj1.x, kj1.y, kj1.z, kj1.w};
        int ia[8] = {ki0.x, ki0.y, ki0.z, ki0.w, ki1.x, ki1.y, ki1.z, ki1.w};

        uint4 aj[8], ai[8];
        #pragma unroll
        for (int u = 0; u < 8; u++)
            aj[u] = *reinterpret_cast<const uint4*>(xtb + (size_t)ja[u] * CC + p * 8);
        #pragma unroll
        for (int u = 0; u < 8; u++)
            ai[u] = *reinterpret_cast<const uint4*>(xtb + (size_t)ia[u] * CC + p * 8);

        #pragma unroll
        for (int u = 0; u < 8; u++) {
            float* m = (u < 4) ? m0 : m1;
            m[0] = fmaxf(m[0], bclo(aj[u].x) - bclo(ai[u].x));
            m[1] = fmaxf(m[1], bchi(aj[u].x) - bchi(ai[u].x));
            m[2] = fmaxf(m[2], bclo(aj[u].y) - bclo(ai[u].y));
            m[3] = fmaxf(m[3], bchi(aj[u].y) - bchi(ai[u].y));
            m[4] = fmaxf(m[4], bclo(aj[u].z) - bclo(ai[u].z));
            m[5] = fmaxf(m[5], bchi(aj[u].z) - bchi(ai[u].z));
            m[6] = fmaxf(m[6], bclo(aj[u].w) - bclo(ai[u].w));
            m[7] = fmaxf(m[7], bchi(aj[u].w) - bchi(ai[u].w));
        }
    }

    // pack h[nl][2c]=x[c], h[nl][2c+1]=m[c]  (32B per lane per batch)
    {
        unsigned xs[8];
        xs[0] = xr0.x & 0xffffu; xs[1] = xr0.x >> 16;
        xs[2] = xr0.y & 0xffffu; xs[3] = xr0.y >> 16;
        xs[4] = xr0.z & 0xffffu; xs[5] = xr0.z >> 16;
        xs[6] = xr0.w & 0xffffu; xs[7] = xr0.w >> 16;
        uint4 lo, hi;
        lo.x = xs[0] | ((unsigned)f2b(m0[0]) << 16);
        lo.y = xs[1] | ((unsigned)f2b(m0[1]) << 16);
        lo.z = xs[2] | ((unsigned)f2b(m0[2]) << 16);
        lo.w = xs[3] | ((unsigned)f2b(m0[3]) << 16);
        hi.x = xs[4] | ((unsigned)f2b(m0[4]) << 16);
        hi.y = xs[5] | ((unsigned)f2b(m0[5]) << 16);
        hi.z = xs[6] | ((unsigned)f2b(m0[6]) << 16);
        hi.w = xs[7] | ((unsigned)f2b(m0[7]) << 16);
        unsigned short* dst = &hl[nl0 * SH + p * 16];
        *reinterpret_cast<uint4*>(dst)     = lo;
        *reinterpret_cast<uint4*>(dst + 8) = hi;
    }
    {
        unsigned xs[8];
        xs[0] = xr1.x & 0xffffu; xs[1] = xr1.x >> 16;
        xs[2] = xr1.y & 0xffffu; xs[3] = xr1.y >> 16;
        xs[4] = xr1.z & 0xffffu; xs[5] = xr1.z >> 16;
        xs[6] = xr1.w & 0xffffu; xs[7] = xr1.w >> 16;
        uint4 lo, hi;
        lo.x = xs[0] | ((unsigned)f2b(m1[0]) << 16);
        lo.y = xs[1] | ((unsigned)f2b(m1[1]) << 16);
        lo.z = xs[2] | ((unsigned)f2b(m1[2]) << 16);
        lo.w = xs[3] | ((unsigned)f2b(m1[3]) << 16);
        hi.x = xs[4] | ((unsigned)f2b(m1[4]) << 16);
        hi.y = xs[5] | ((unsigned)f2b(m1[5]) << 16);
        hi.z = xs[6] | ((unsigned)f2b(m1[6]) << 16);
        hi.w = xs[7] | ((unsigned)f2b(m1[7]) << 16);
        unsigned short* dst = &hl[nl1 * SH + p * 16];
        *reinterpret_cast<uint4*>(dst)     = lo;
        *reinterpret_cast<uint4*>(dst + 8) = hi;
    }

    // ---- A-fragments: loaded here (post-gather) so their VGPRs aren't live
    //      during phase 1; loads overlap the barrier drain ----
    const int quad = lane >> 4;
    const int l15  = lane & 15;
    const int o0w  = w * 32;
    bf16x8 afr[2][4];
    #pragma unroll
    for (int ot = 0; ot < 2; ot++)
        #pragma unroll
        for (int ks = 0; ks < 4; ks++)
            afr[ot][ks] = *reinterpret_cast<const bf16x8*>(
                Wbf + (o0w + ot * 16 + l15) * OO + ks * 32 + quad * 8);

    __syncthreads();

    // ---- phase 2: out[128 x 64] = W[128x128] @ h[128x64], MFMA bf16 ----
    #pragma unroll
    for (int nt = 0; nt < 4; nt++) {
        f32x4 acc0 = {0.f, 0.f, 0.f, 0.f};
        f32x4 acc1 = {0.f, 0.f, 0.f, 0.f};
        #pragma unroll
        for (int ks = 0; ks < 4; ks++) {
            const unsigned short* bp = &hl[(nt * 16 + l15) * SH + ks * 32 + quad * 8];
            bf16x8 bfr = *reinterpret_cast<const bf16x8*>(bp);
            acc0 = __builtin_amdgcn_mfma_f32_16x16x32_bf16(afr[0][ks], bfr, acc0, 0, 0, 0);
            acc1 = __builtin_amdgcn_mfma_f32_16x16x32_bf16(afr[1][ks], bfr, acc1, 0, 0, 0);
        }
        int n_g = n_base + nt * 16 + l15;
        #pragma unroll
        for (int r = 0; r < 4; r++) {
            int o_a = o0w + quad * 4 + r;
            int o_b = o0w + 16 + quad * 4 + r;
            float va = acc0[r] + bias[o_a];
            float vb = acc1[r] + bias[o_b];
            out[((size_t)b * OO + o_a) * NN + n_g] = fmaxf(va, 0.f);
            out[((size_t)b * OO + o_b) * NN + n_g] = fmaxf(vb, 0.f);
        }
    }
}

extern "C" void kernel_launch(void* const* d_in, const int* in_sizes, int n_in,
                              void* d_out, int out_size, void* d_ws, size_t ws_size,
                              hipStream_t stream) {
    const float* x    = (const float*)d_in[0];
    const int*   eidx = (const int*)d_in[1];
    const float* W    = (const float*)d_in[2];
    const float* bias = (const float*)d_in[3];
    float* out = (float*)d_out;

    unsigned short* xt  = (unsigned short*)d_ws;                            // 4 MB
    unsigned short* Wbf = (unsigned short*)((char*)d_ws + 4 * 1024 * 1024); // 32 KB

    dim3 blk(256);
    dim3 grid(512);
    transpose_kernel<<<grid, blk, 0, stream>>>(x, xt, W, Wbf);
    main_kernel<<<grid, blk, 0, stream>>>(xt, Wbf, eidx, bias, out);
}